// Round 17
// baseline (100.498 us; speedup 1.0000x reference)
//
#include <hip/hip_runtime.h>
#include <stdint.h>

// Problem: B=2, T=2048, C=1024, H=16, HD=64. M = B*T = 4096, 3C = 3072.
// Geo bias folded into Q:  q~[d] = q[d]*SCALE + hs*(q[:8]·dir)*dir[d] (d<8)
// log2(e) additionally folded into Q~ so softmax uses exp2 directly.
// Softmax is MAX-FREE: P = exp2(S') directly (S' provably < ~25 << 127).
// PV without any P LDS bounce, using ONLY the proven 16x16x32 MFMA: operand
// slot (g,i) is defined as k = ct0*16+4g+i (i<4) / ct1*16+4g+(i-4) (i>=4) for
// BOTH A (V) and B (P) -> one K=32 MFMA contracts two QK ct-chunks. P operand
// is assembled in registers from cvtpk of the QK C-layout (which already holds
// the 4 per-chunk k-values per lane); V operand = two hoisted ds_read_b64.

typedef float f32x4 __attribute__((ext_vector_type(4)));
typedef unsigned short u16x8 __attribute__((ext_vector_type(8)));
typedef unsigned short u16x4 __attribute__((ext_vector_type(4)));
typedef unsigned int u32x2 __attribute__((ext_vector_type(2)));
typedef unsigned int u32x4 __attribute__((ext_vector_type(4)));
typedef __bf16 bf16x8 __attribute__((ext_vector_type(8)));

static __device__ __forceinline__ unsigned short f2bf(float f) {
  unsigned u = __float_as_uint(f);
  u += 0x7FFFu + ((u >> 16) & 1u);
  return (unsigned short)(u >> 16);
}
static __device__ __forceinline__ float bf2f(unsigned short s) {
  return __uint_as_float(((unsigned)s) << 16);
}
static __device__ __forceinline__ f32x4 mfma16(u16x8 a, u16x8 b, f32x4 c) {
  return __builtin_amdgcn_mfma_f32_16x16x32_bf16(
      __builtin_bit_cast(bf16x8, a), __builtin_bit_cast(bf16x8, b), c, 0, 0, 0);
}
static __device__ __forceinline__ unsigned cvtpk(float lo, float hi) {
  unsigned d;
  asm("v_cvt_pk_bf16_f32 %0, %1, %2" : "=v"(d) : "v"(lo), "v"(hi));
  return d;
}

#define GLD16(gp, lp) __builtin_amdgcn_global_load_lds( \
    (const __attribute__((address_space(1))) unsigned int*)(gp), \
    (__attribute__((address_space(3))) unsigned int*)(lp), 16, 0, 0)

// ---------------- fused prep: cast x->bf16 ; transpose+cast wqkv, wout ----------------
__global__ __launch_bounds__(256) void k_prep(const float* __restrict__ x,
                                              const float* __restrict__ wqkv,
                                              const float* __restrict__ wout,
                                              unsigned short* __restrict__ xb,
                                              unsigned short* __restrict__ wqkvT,
                                              unsigned short* __restrict__ woutT) {
  __shared__ float t[64][65];
  const int bid = blockIdx.x;
  if (bid < 4096) {
    int i = bid * 256 + threadIdx.x;
    f32x4 v = *(const f32x4*)(x + (size_t)i * 4);
    u16x4 o;
#pragma unroll
    for (int j = 0; j < 4; ++j) o[j] = f2bf(v[j]);
    *(u16x4*)(xb + (size_t)i * 4) = o;
    return;
  }
  const float* in;
  unsigned short* out;
  int Cc, bx, by;
  if (bid < 4864) {
    int tt = bid - 4096;
    in = wqkv; out = wqkvT; Cc = 3072;
    bx = tt % 48; by = tt / 48;
  } else {
    int tt = bid - 4864;
    in = wout; out = woutT; Cc = 1024;
    bx = tt & 15; by = tt >> 4;
  }
  const int R = 1024;
  int tr = by * 64, tc = bx * 64;
  int tx = threadIdx.x & 15, ty = threadIdx.x >> 4;
#pragma unroll
  for (int i = 0; i < 4; ++i) {
    int rr = ty + i * 16;
    f32x4 v = *(const f32x4*)(in + (size_t)(tr + rr) * Cc + tc + tx * 4);
#pragma unroll
    for (int j = 0; j < 4; ++j) t[rr][tx * 4 + j] = v[j];
  }
  __syncthreads();
#pragma unroll
  for (int i = 0; i < 4; ++i) {
    int cc = ty + i * 16;
    int rr = tx * 4;
    u16x4 o;
#pragma unroll
    for (int j = 0; j < 4; ++j) o[j] = f2bf(t[rr + j][cc]);
    *(u16x4*)(out + (size_t)(tc + cc) * R + tr + rr) = o;
  }
}

// ---------------- QKV GEMM: C[m][n] = sum_k A[m][k]*Bt[n][k]  (128x128, BK=64, swizzled)
__global__ __launch_bounds__(256) void k_gemm_qkv(const unsigned short* __restrict__ A,
                                                  const unsigned short* __restrict__ Bt,
                                                  unsigned short* __restrict__ qo,
                                                  unsigned short* __restrict__ ko,
                                                  unsigned short* __restrict__ vTo) {
  __shared__ unsigned short lA[128 * 64];   // 16 KB, XOR-swizzled rows
  __shared__ unsigned short lB[128 * 64];   // 16 KB
  const int tid = threadIdx.x;
  const int lane = tid & 63, wid = tid >> 6;
  const int wr = wid >> 1, wc = wid & 1;
  const int r = lane & 15, g = lane >> 4;
  const int mbase = blockIdx.y * 128;
  const int nbase = blockIdx.x * 128;
  const int rsw = (r & 7) << 4;

  f32x4 acc[4][4] = {};

  for (int kt = 0; kt < 16; ++kt) {
    __syncthreads();
#pragma unroll
    for (int p = 0; p < 4; ++p) {
      int L = p * 4096 + tid * 16;  // byte offset in 16KB tile [128][64]bf16
      int row = L >> 7;             // 128B rows (64 bf16)
      int cb = (L >> 4) & 7;
      int cbg = cb ^ (row & 7);     // pre-swizzled source -> swizzled reads
      GLD16(A + (size_t)(mbase + row) * 1024 + kt * 64 + cbg * 8, lA + (L >> 1));
      GLD16(Bt + (size_t)(nbase + row) * 1024 + kt * 64 + cbg * 8, lB + (L >> 1));
    }
    __syncthreads();
#pragma unroll
    for (int s = 0; s < 2; ++s) {
      u16x8 af[4], bfv[4];
      const int csw = (s * 64 + g * 16) ^ rsw;
#pragma unroll
      for (int m = 0; m < 4; ++m)
        af[m] = *(const u16x8*)((const char*)lA + (wr * 64 + m * 16 + r) * 128 + csw);
#pragma unroll
      for (int n = 0; n < 4; ++n)
        bfv[n] = *(const u16x8*)((const char*)lB + (wc * 64 + n * 16 + r) * 128 + csw);
#pragma unroll
      for (int m = 0; m < 4; ++m)
#pragma unroll
        for (int n = 0; n < 4; ++n) acc[m][n] = mfma16(af[m], bfv[n], acc[m][n]);
    }
  }

#pragma unroll
  for (int m = 0; m < 4; ++m) {
#pragma unroll
    for (int n = 0; n < 4; ++n) {
      int ng = nbase + wc * 64 + n * 16 + r;
      int m0 = mbase + wr * 64 + m * 16 + g * 4;
      int sec = ng >> 10, rem = ng & 1023, hh = rem >> 6, d = rem & 63;
      int b = m0 >> 11, t0 = m0 & 2047;
      size_t bh = (size_t)(b * 16 + hh);
      if (sec == 2) {
        u16x4 o;
#pragma unroll
        for (int e = 0; e < 4; ++e) o[e] = f2bf(acc[m][n][e]);
        *(u16x4*)(vTo + (bh * 64 + d) * 2048 + t0) = o;  // V^T: [bh][d][t]
      } else {
        unsigned short* dst = (sec == 0 ? qo : ko);
#pragma unroll
        for (int e = 0; e < 4; ++e)
          dst[(bh * 2048 + t0 + e) * 64 + d] = f2bf(acc[m][n][e]);
      }
    }
  }
}

// ---------------- output GEMM: 128M x 64N tiles, 512 blocks = 2/CU (R14 win) ----------------
__global__ __launch_bounds__(256) void k_gout(const unsigned short* __restrict__ A,
                                              const unsigned short* __restrict__ Bt,
                                              float* __restrict__ fo) {
  __shared__ unsigned short lA[128 * 64];   // 16 KB, XOR-swizzled rows
  __shared__ unsigned short lB[64 * 64];    //  8 KB
  const int tid = threadIdx.x;
  const int lane = tid & 63, wid = tid >> 6;
  const int wr = wid >> 1, wc = wid & 1;    // 2x2 wave grid
  const int r = lane & 15, g = lane >> 4;
  const int mbase = blockIdx.y * 128;       // M/128 = 32
  const int nbase = blockIdx.x * 64;        // N/64  = 16
  const int rsw = (r & 7) << 4;

  f32x4 acc[4][2] = {};

  for (int kt = 0; kt < 16; ++kt) {
    __syncthreads();
#pragma unroll
    for (int p = 0; p < 4; ++p) {
      int L = p * 4096 + tid * 16;
      int row = L >> 7;             // 128B rows (64 bf16)
      int cb = (L >> 4) & 7;
      int cbg = cb ^ (row & 7);     // pre-swizzled source -> swizzled reads
      GLD16(A + (size_t)(mbase + row) * 1024 + kt * 64 + cbg * 8, lA + (L >> 1));
      if (p < 2)
        GLD16(Bt + (size_t)(nbase + row) * 1024 + kt * 64 + cbg * 8, lB + (L >> 1));
    }
    __syncthreads();
#pragma unroll
    for (int s = 0; s < 2; ++s) {
      u16x8 af[4], bfv[2];
      const int csw = (s * 64 + g * 16) ^ rsw;
#pragma unroll
      for (int m = 0; m < 4; ++m)
        af[m] = *(const u16x8*)((const char*)lA + (wr * 64 + m * 16 + r) * 128 + csw);
#pragma unroll
      for (int n = 0; n < 2; ++n)
        bfv[n] = *(const u16x8*)((const char*)lB + (wc * 32 + n * 16 + r) * 128 + csw);
#pragma unroll
      for (int m = 0; m < 4; ++m)
#pragma unroll
        for (int n = 0; n < 2; ++n) acc[m][n] = mfma16(af[m], bfv[n], acc[m][n]);
    }
  }

#pragma unroll
  for (int m = 0; m < 4; ++m)
#pragma unroll
    for (int n = 0; n < 2; ++n) {
      int ng = nbase + wc * 32 + n * 16 + r;
      int m0 = mbase + wr * 64 + m * 16 + g * 4;
#pragma unroll
      for (int e = 0; e < 4; ++e)
        fo[(size_t)(m0 + e) * 1024 + ng] = acc[m][n][e];
    }
}

// ---------------- causal flash attention, head_dim 64, folded E8 bias ----------------
// R13 structure + slot-packed PV: one 16x16x32 MFMA contracts two ct-chunks
// (P packed from registers, V from two ds_read_b64) -> no P LDS bounce, no
// mid-iter lgkm drain. LDS 32KB (K/V double-buffer only).
__global__ __launch_bounds__(256, 4) void k_attn(const unsigned short* __restrict__ qb,
                                                 const unsigned short* __restrict__ kb,
                                                 const unsigned short* __restrict__ vTb,
                                                 const float* __restrict__ hsc,
                                                 const float* __restrict__ hdir,
                                                 unsigned short* __restrict__ o2) {
  __shared__ unsigned short lK[2][64 * 64];   // [buf][kpos][d], XOR-swizzled rows
  __shared__ unsigned short lV[2][64 * 64];   // [buf][d][kpos], XOR-swizzled rows

  const int tid = threadIdx.x, lane = tid & 63, wid = tid >> 6;
  const int r = lane & 15, g = lane >> 4;
  const int bid = blockIdx.x;
  const int u = bid & 255, kq = bid >> 8;
  const int bh = u & 31, j = u >> 5;  // j in 0..7
  const int a = (kq == 0) ? j : (kq == 1) ? (31 - j) : (kq == 2) ? (8 + j) : (23 - j);
  const int nk = a + 1;
  const int qbase = a * 64;
  const int h = bh & 15, bi = bh >> 4;

  const size_t kbase = (size_t)bh * (2048 * 64);
  const size_t vbase = (size_t)bh * (64 * 2048);

  // --- staging pointers: strength-reduced, advance by constant stride per tile ---
  const int L0 = tid * 16, L1 = 4096 + tid * 16;
  const int sr0 = L0 >> 7, sr1 = L1 >> 7;              // 128B rows
  const int sc0 = ((L0 >> 4) & 7) ^ (sr0 & 7);         // pre-swizzled source col
  const int sc1 = ((L1 >> 4) & 7) ^ (sr1 & 7);
  const unsigned short* kG0 = kb + kbase + (size_t)sr0 * 64 + sc0 * 8;
  const unsigned short* kG1 = kb + kbase + (size_t)sr1 * 64 + sc1 * 8;
  const unsigned short* vG0 = vTb + vbase + (size_t)sr0 * 2048 + sc0 * 8;
  const unsigned short* vG1 = vTb + vbase + (size_t)sr1 * 2048 + sc1 * 8;
  unsigned short* const dK0a = (unsigned short*)lK[0] + (L0 >> 1);
  unsigned short* const dK0b = (unsigned short*)lK[0] + (L1 >> 1);
  unsigned short* const dK1a = (unsigned short*)lK[1] + (L0 >> 1);
  unsigned short* const dK1b = (unsigned short*)lK[1] + (L1 >> 1);
  unsigned short* const dV0a = (unsigned short*)lV[0] + (L0 >> 1);
  unsigned short* const dV0b = (unsigned short*)lV[0] + (L1 >> 1);
  unsigned short* const dV1a = (unsigned short*)lV[1] + (L0 >> 1);
  unsigned short* const dV1b = (unsigned short*)lV[1] + (L1 >> 1);

#define ATTN_STAGE(B) do {                        \
    GLD16(kG0, dK##B##a); GLD16(kG1, dK##B##b);   \
    GLD16(vG0, dV##B##a); GLD16(vG1, dV##B##b);   \
    kG0 += 4096; kG1 += 4096; vG0 += 64; vG1 += 64; } while (0)

  ATTN_STAGE(0);  // stage tile 0 (overlaps Q build below); ptrs now at tile 1

  const float LOG2E = 1.44269504088896f;
  const float hs = hsc[h];
  float dir8[8];
#pragma unroll
  for (int j2 = 0; j2 < 8; ++j2) dir8[j2] = hdir[h * 8 + j2];

  // Folded Q~ fragment (B-operand of swapped QK^T): lane holds Q~[q=r][d-chunk g].
  u16x8 qc0, qc1;
  {
    const unsigned short* qrow = qb + ((size_t)bh * 2048 + qbase + wid * 16 + r) * 64;
    float proj = 0.f;
    u16x8 qv = *(const u16x8*)qrow;
#pragma unroll
    for (int j2 = 0; j2 < 8; ++j2) proj += bf2f(qv[j2]) * dir8[j2];
#pragma unroll
    for (int s = 0; s < 2; ++s) {
      u16x8 raw = *(const u16x8*)(qrow + s * 32 + g * 8);
      u16x8 ov;
#pragma unroll
      for (int j2 = 0; j2 < 8; ++j2) {
        float v = bf2f(raw[j2]) * (0.125f * LOG2E);
        if (s == 0 && g == 0) v += (hs * LOG2E) * proj * dir8[j2];
        ov[j2] = f2bf(v);
      }
      if (s == 0) qc0 = ov; else qc1 = ov;
    }
  }

  // --- hoisted LDS fragment pointers (loop-invariant; literal indexing only) ---
  const u16x8* kp[2][8];
  const u16x4* vk[2][16];   // [buf][ct*4+dt]: V^T[d=dt*16+r][k=ct*16+g*4..+3]
#pragma unroll
  for (int b = 0; b < 2; ++b) {
    const char* kc = (const char*)lK[b];
    const char* vc = (const char*)lV[b];
#pragma unroll
    for (int ct = 0; ct < 4; ++ct) {
      int krow = ct * 16 + r, sw = (krow & 7) << 4;
      kp[b][ct * 2 + 0] = (const u16x8*)(kc + krow * 128 + ((g * 16) ^ sw));
      kp[b][ct * 2 + 1] = (const u16x8*)(kc + krow * 128 + ((64 + g * 16) ^ sw));
    }
#pragma unroll
    for (int ct = 0; ct < 4; ++ct)
#pragma unroll
      for (int dt = 0; dt < 4; ++dt) {
        int dd = dt * 16 + r;
        // 8B-granule read: XOR touches byte bits 4-6 only, bit 3 preserved.
        vk[b][ct * 4 + dt] =
            (const u16x4*)(vc + dd * 128 + ((ct * 32 + g * 8) ^ ((dd & 7) << 4)));
      }
  }

  f32x4 accO[4] = {};
  float lp = 0.f;   // LANE-PARTIAL denominator (reduced once in epilogue)
  const int qq = qbase + wid * 16 + r;

  // prologue: tile 0 staged & published
  asm volatile("s_waitcnt vmcnt(0)" ::: "memory");
  __builtin_amdgcn_sched_barrier(0);
  __builtin_amdgcn_s_barrier();

#define ATTN_BODY(B, KT) do {                                                  \
    f32x4 accS[4];                                                             \
    __builtin_amdgcn_s_setprio(1);                                             \
    _Pragma("unroll")                                                          \
    for (int ct = 0; ct < 4; ++ct) {                                           \
      f32x4 s4 = {0.f, 0.f, 0.f, 0.f};                                         \
      s4 = mfma16(*kp[B][ct * 2 + 0], qc0, s4);                                \
      s4 = mfma16(*kp[B][ct * 2 + 1], qc1, s4);                                \
      accS[ct] = s4;                                                           \
    }                                                                          \
    __builtin_amdgcn_s_setprio(0);                                             \
    if ((KT) == nk - 1) {                                                      \
      _Pragma("unroll")                                                        \
      for (int ct = 0; ct < 4; ++ct)                                           \
        _Pragma("unroll")                                                      \
        for (int e = 0; e < 4; ++e) {                                          \
          int kk = (KT) * 64 + ct * 16 + g * 4 + e;                            \
          if (kk > qq) accS[ct][e] = -1e30f;                                   \
        }                                                                      \
    }                                                                          \
    __builtin_amdgcn_s_setprio(1);                                             \
    _Pragma("unroll")                                                          \
    for (int cp = 0; cp < 2; ++cp) {                                           \
      const int c0 = cp * 2, c1 = cp * 2 + 1;                                  \
      float a0 = exp2f(accS[c0][0]), a1 = exp2f(accS[c0][1]);                  \
      float a2 = exp2f(accS[c0][2]), a3 = exp2f(accS[c0][3]);                  \
      float b0 = exp2f(accS[c1][0]), b1 = exp2f(accS[c1][1]);                  \
      float b2 = exp2f(accS[c1][2]), b3 = exp2f(accS[c1][3]);                  \
      lp += ((a0 + a1) + (a2 + a3)) + ((b0 + b1) + (b2 + b3));                 \
      u32x4 wp;                                                                \
      wp[0] = cvtpk(a0, a1);                                                   \
      wp[1] = cvtpk(a2, a3);                                                   \
      wp[2] = cvtpk(b0, b1);                                                   \
      wp[3] = cvtpk(b2, b3);                                                   \
      u16x8 pa = __builtin_bit_cast(u16x8, wp);                                \
      _Pragma("unroll")                                                        \
      for (int dt = 0; dt < 4; ++dt) {                                         \
        u16x4 lo = *vk[B][c0 * 4 + dt];                                        \
        u16x4 hi = *vk[B][c1 * 4 + dt];                                        \
        u16x8 vv = __builtin_shufflevector(lo, hi, 0, 1, 2, 3, 4, 5, 6, 7);    \
        accO[dt] = mfma16(vv, pa, accO[dt]);                                   \
      }                                                                        \
    }                                                                          \
    __builtin_amdgcn_s_setprio(0);                                             \
  } while (0)

#define ATTN_SYNC() do {                                  \
    asm volatile("s_waitcnt vmcnt(0)" ::: "memory");      \
    __builtin_amdgcn_sched_barrier(0);                    \
    __builtin_amdgcn_s_barrier(); } while (0)

  int kt = 0;
  for (;;) {
    if (kt + 1 < nk) ATTN_STAGE(1);
    ATTN_BODY(0, kt);
    ++kt; if (kt == nk) break;
    ATTN_SYNC();
    if (kt + 1 < nk) ATTN_STAGE(0);
    ATTN_BODY(1, kt);
    ++kt; if (kt == nk) break;
    ATTN_SYNC();
  }
#undef ATTN_BODY
#undef ATTN_STAGE
#undef ATTN_SYNC

  // epilogue: reduce lane-partial l once, then O/l -> bf16 [B,T,C]
  lp += __shfl_xor(lp, 16, 64);
  lp += __shfl_xor(lp, 32, 64);
  float inv = 1.f / lp;
#pragma unroll
  for (int dt = 0; dt < 4; ++dt) {
    u16x4 o;
#pragma unroll
    for (int e = 0; e < 4; ++e) o[e] = f2bf(accO[dt][e] * inv);
    *(u16x4*)(o2 + ((size_t)(bi * 2048 + qq)) * 1024 + h * 64 + dt * 16 + g * 4) = o;
  }
}

extern "C" void kernel_launch(void* const* d_in, const int* in_sizes, int n_in,
                              void* d_out, int out_size, void* d_ws, size_t ws_size,
                              hipStream_t stream) {
  const float* x    = (const float*)d_in[0];
  const float* wqkv = (const float*)d_in[1];
  const float* wout = (const float*)d_in[2];
  const float* hsc  = (const float*)d_in[3];
  const float* hdir = (const float*)d_in[4];
  float* outp = (float*)d_out;

  char* ws = (char*)d_ws;
  unsigned short* xb    = (unsigned short*)(ws + 0);         //  8 MB  [4096][1024]
  unsigned short* wqkvT = (unsigned short*)(ws + 8388608);   //  6 MB  [3072][1024]
  unsigned short* woutT = (unsigned short*)(ws + 14680064);  //  2 MB  [1024][1024]
  unsigned short* qb    = (unsigned short*)(ws + 16777216);  //  8 MB  [32][2048][64]
  unsigned short* kb    = (unsigned short*)(ws + 25165824);  //  8 MB  [32][2048][64]
  unsigned short* vT    = (unsigned short*)(ws + 33554432);  //  8 MB  [32][64][2048]
  unsigned short* x2b   = (unsigned short*)(ws + 41943040);  //  8 MB  [4096][1024]
  if (ws_size < 50331648u) return;

  k_prep<<<5120, 256, 0, stream>>>(x, wqkv, wout, xb, wqkvT, woutT);
  k_gemm_qkv<<<dim3(24, 32), 256, 0, stream>>>(xb, wqkvT, qb, kb, vT);
  k_attn<<<dim3(1024), 256, 0, stream>>>(qb, kb, vT, hsc, hdir, x2b);
  k_gout<<<dim3(16, 32), 256, 0, stream>>>(x2b, woutT, outp);
}

// Round 18
// 99.002 us; speedup vs baseline: 1.0151x; 1.0151x over previous
//
#include <hip/hip_runtime.h>
#include <stdint.h>

// Problem: B=2, T=2048, C=1024, H=16, HD=64. M = B*T = 4096, 3C = 3072.
// Geo bias folded into Q:  q~[d] = q[d]*SCALE + hs*(q[:8]·dir)*dir[d] (d<8)
// log2(e) additionally folded into Q~ so softmax uses exp2 directly.
// Softmax is MAX-FREE: P = exp2(S') directly (S' provably < ~25 << 127).
// Best-known config (R14): R13 attn (P-bounce, hoisted addrs, single barrier)
// + BK=64 swizzled GEMMs. R15-17 P-bypass variants regressed -> reverted.

typedef float f32x4 __attribute__((ext_vector_type(4)));
typedef unsigned short u16x8 __attribute__((ext_vector_type(8)));
typedef unsigned short u16x4 __attribute__((ext_vector_type(4)));
typedef unsigned int u32x2 __attribute__((ext_vector_type(2)));
typedef __bf16 bf16x8 __attribute__((ext_vector_type(8)));

static __device__ __forceinline__ unsigned short f2bf(float f) {
  unsigned u = __float_as_uint(f);
  u += 0x7FFFu + ((u >> 16) & 1u);
  return (unsigned short)(u >> 16);
}
static __device__ __forceinline__ float bf2f(unsigned short s) {
  return __uint_as_float(((unsigned)s) << 16);
}
static __device__ __forceinline__ f32x4 mfma16(u16x8 a, u16x8 b, f32x4 c) {
  return __builtin_amdgcn_mfma_f32_16x16x32_bf16(
      __builtin_bit_cast(bf16x8, a), __builtin_bit_cast(bf16x8, b), c, 0, 0, 0);
}
static __device__ __forceinline__ unsigned cvtpk(float lo, float hi) {
  unsigned d;
  asm("v_cvt_pk_bf16_f32 %0, %1, %2" : "=v"(d) : "v"(lo), "v"(hi));
  return d;
}

#define GLD16(gp, lp) __builtin_amdgcn_global_load_lds( \
    (const __attribute__((address_space(1))) unsigned int*)(gp), \
    (__attribute__((address_space(3))) unsigned int*)(lp), 16, 0, 0)

// ---------------- fused prep: cast x->bf16 ; transpose+cast wqkv, wout ----------------
__global__ __launch_bounds__(256) void k_prep(const float* __restrict__ x,
                                              const float* __restrict__ wqkv,
                                              const float* __restrict__ wout,
                                              unsigned short* __restrict__ xb,
                                              unsigned short* __restrict__ wqkvT,
                                              unsigned short* __restrict__ woutT) {
  __shared__ float t[64][65];
  const int bid = blockIdx.x;
  if (bid < 4096) {
    int i = bid * 256 + threadIdx.x;
    f32x4 v = *(const f32x4*)(x + (size_t)i * 4);
    u16x4 o;
#pragma unroll
    for (int j = 0; j < 4; ++j) o[j] = f2bf(v[j]);
    *(u16x4*)(xb + (size_t)i * 4) = o;
    return;
  }
  const float* in;
  unsigned short* out;
  int Cc, bx, by;
  if (bid < 4864) {
    int tt = bid - 4096;
    in = wqkv; out = wqkvT; Cc = 3072;
    bx = tt % 48; by = tt / 48;
  } else {
    int tt = bid - 4864;
    in = wout; out = woutT; Cc = 1024;
    bx = tt & 15; by = tt >> 4;
  }
  const int R = 1024;
  int tr = by * 64, tc = bx * 64;
  int tx = threadIdx.x & 15, ty = threadIdx.x >> 4;
#pragma unroll
  for (int i = 0; i < 4; ++i) {
    int rr = ty + i * 16;
    f32x4 v = *(const f32x4*)(in + (size_t)(tr + rr) * Cc + tc + tx * 4);
#pragma unroll
    for (int j = 0; j < 4; ++j) t[rr][tx * 4 + j] = v[j];
  }
  __syncthreads();
#pragma unroll
  for (int i = 0; i < 4; ++i) {
    int cc = ty + i * 16;
    int rr = tx * 4;
    u16x4 o;
#pragma unroll
    for (int j = 0; j < 4; ++j) o[j] = f2bf(t[rr + j][cc]);
    *(u16x4*)(out + (size_t)(tc + cc) * R + tr + rr) = o;
  }
}

// ---------------- QKV GEMM: C[m][n] = sum_k A[m][k]*Bt[n][k]  (128x128, BK=64, swizzled)
__global__ __launch_bounds__(256) void k_gemm_qkv(const unsigned short* __restrict__ A,
                                                  const unsigned short* __restrict__ Bt,
                                                  unsigned short* __restrict__ qo,
                                                  unsigned short* __restrict__ ko,
                                                  unsigned short* __restrict__ vTo) {
  __shared__ unsigned short lA[128 * 64];   // 16 KB, XOR-swizzled rows
  __shared__ unsigned short lB[128 * 64];   // 16 KB
  const int tid = threadIdx.x;
  const int lane = tid & 63, wid = tid >> 6;
  const int wr = wid >> 1, wc = wid & 1;
  const int r = lane & 15, g = lane >> 4;
  const int mbase = blockIdx.y * 128;
  const int nbase = blockIdx.x * 128;
  const int rsw = (r & 7) << 4;

  f32x4 acc[4][4] = {};

  for (int kt = 0; kt < 16; ++kt) {
    __syncthreads();
#pragma unroll
    for (int p = 0; p < 4; ++p) {
      int L = p * 4096 + tid * 16;  // byte offset in 16KB tile [128][64]bf16
      int row = L >> 7;             // 128B rows (64 bf16)
      int cb = (L >> 4) & 7;
      int cbg = cb ^ (row & 7);     // pre-swizzled source -> swizzled reads
      GLD16(A + (size_t)(mbase + row) * 1024 + kt * 64 + cbg * 8, lA + (L >> 1));
      GLD16(Bt + (size_t)(nbase + row) * 1024 + kt * 64 + cbg * 8, lB + (L >> 1));
    }
    __syncthreads();
#pragma unroll
    for (int s = 0; s < 2; ++s) {
      u16x8 af[4], bfv[4];
      const int csw = (s * 64 + g * 16) ^ rsw;
#pragma unroll
      for (int m = 0; m < 4; ++m)
        af[m] = *(const u16x8*)((const char*)lA + (wr * 64 + m * 16 + r) * 128 + csw);
#pragma unroll
      for (int n = 0; n < 4; ++n)
        bfv[n] = *(const u16x8*)((const char*)lB + (wc * 64 + n * 16 + r) * 128 + csw);
#pragma unroll
      for (int m = 0; m < 4; ++m)
#pragma unroll
        for (int n = 0; n < 4; ++n) acc[m][n] = mfma16(af[m], bfv[n], acc[m][n]);
    }
  }

#pragma unroll
  for (int m = 0; m < 4; ++m) {
#pragma unroll
    for (int n = 0; n < 4; ++n) {
      int ng = nbase + wc * 64 + n * 16 + r;
      int m0 = mbase + wr * 64 + m * 16 + g * 4;
      int sec = ng >> 10, rem = ng & 1023, hh = rem >> 6, d = rem & 63;
      int b = m0 >> 11, t0 = m0 & 2047;
      size_t bh = (size_t)(b * 16 + hh);
      if (sec == 2) {
        u16x4 o;
#pragma unroll
        for (int e = 0; e < 4; ++e) o[e] = f2bf(acc[m][n][e]);
        *(u16x4*)(vTo + (bh * 64 + d) * 2048 + t0) = o;  // V^T: [bh][d][t]
      } else {
        unsigned short* dst = (sec == 0 ? qo : ko);
#pragma unroll
        for (int e = 0; e < 4; ++e)
          dst[(bh * 2048 + t0 + e) * 64 + d] = f2bf(acc[m][n][e]);
      }
    }
  }
}

// ---------------- output GEMM: 128M x 64N tiles, 512 blocks = 2/CU (R14 win) ----------------
__global__ __launch_bounds__(256) void k_gout(const unsigned short* __restrict__ A,
                                              const unsigned short* __restrict__ Bt,
                                              float* __restrict__ fo) {
  __shared__ unsigned short lA[128 * 64];   // 16 KB, XOR-swizzled rows
  __shared__ unsigned short lB[64 * 64];    //  8 KB
  const int tid = threadIdx.x;
  const int lane = tid & 63, wid = tid >> 6;
  const int wr = wid >> 1, wc = wid & 1;    // 2x2 wave grid
  const int r = lane & 15, g = lane >> 4;
  const int mbase = blockIdx.y * 128;       // M/128 = 32
  const int nbase = blockIdx.x * 64;        // N/64  = 16
  const int rsw = (r & 7) << 4;

  f32x4 acc[4][2] = {};

  for (int kt = 0; kt < 16; ++kt) {
    __syncthreads();
#pragma unroll
    for (int p = 0; p < 4; ++p) {
      int L = p * 4096 + tid * 16;
      int row = L >> 7;             // 128B rows (64 bf16)
      int cb = (L >> 4) & 7;
      int cbg = cb ^ (row & 7);     // pre-swizzled source -> swizzled reads
      GLD16(A + (size_t)(mbase + row) * 1024 + kt * 64 + cbg * 8, lA + (L >> 1));
      if (p < 2)
        GLD16(Bt + (size_t)(nbase + row) * 1024 + kt * 64 + cbg * 8, lB + (L >> 1));
    }
    __syncthreads();
#pragma unroll
    for (int s = 0; s < 2; ++s) {
      u16x8 af[4], bfv[2];
      const int csw = (s * 64 + g * 16) ^ rsw;
#pragma unroll
      for (int m = 0; m < 4; ++m)
        af[m] = *(const u16x8*)((const char*)lA + (wr * 64 + m * 16 + r) * 128 + csw);
#pragma unroll
      for (int n = 0; n < 2; ++n)
        bfv[n] = *(const u16x8*)((const char*)lB + (wc * 32 + n * 16 + r) * 128 + csw);
#pragma unroll
      for (int m = 0; m < 4; ++m)
#pragma unroll
        for (int n = 0; n < 2; ++n) acc[m][n] = mfma16(af[m], bfv[n], acc[m][n]);
    }
  }

#pragma unroll
  for (int m = 0; m < 4; ++m)
#pragma unroll
    for (int n = 0; n < 2; ++n) {
      int ng = nbase + wc * 32 + n * 16 + r;
      int m0 = mbase + wr * 64 + m * 16 + g * 4;
#pragma unroll
      for (int e = 0; e < 4; ++e)
        fo[(size_t)(m0 + e) * 1024 + ng] = acc[m][n][e];
    }
}

// ---------------- causal flash attention, head_dim 64, folded E8 bias ----------------
// R13 form (best found, 44.7us): 1024 blocks x 4 waves, 64 q-rows, 40KB LDS ->
// 4 blocks/CU; single barrier/iter (T3 order); max-free softmax; all LDS/global
// addresses hoisted, K-loop unrolled x2 (compile-time dbuf index).
__global__ __launch_bounds__(256, 4) void k_attn(const unsigned short* __restrict__ qb,
                                                 const unsigned short* __restrict__ kb,
                                                 const unsigned short* __restrict__ vTb,
                                                 const float* __restrict__ hsc,
                                                 const float* __restrict__ hdir,
                                                 unsigned short* __restrict__ o2) {
  __shared__ unsigned short lK[2][64 * 64];   // [buf][kpos][d], XOR-swizzled rows
  __shared__ unsigned short lV[2][64 * 64];   // [buf][d][kpos], XOR-swizzled rows
  __shared__ unsigned short lP[4][16 * 64];   // per-wave P bounce, swizzled

  const int tid = threadIdx.x, lane = tid & 63, wid = tid >> 6;
  const int r = lane & 15, g = lane >> 4;
  const int bid = blockIdx.x;
  const int u = bid & 255, kq = bid >> 8;
  const int bh = u & 31, j = u >> 5;  // j in 0..7
  const int a = (kq == 0) ? j : (kq == 1) ? (31 - j) : (kq == 2) ? (8 + j) : (23 - j);
  const int nk = a + 1;
  const int qbase = a * 64;
  const int h = bh & 15, bi = bh >> 4;

  const size_t kbase = (size_t)bh * (2048 * 64);
  const size_t vbase = (size_t)bh * (64 * 2048);

  // --- staging pointers: strength-reduced, advance by constant stride per tile ---
  const int L0 = tid * 16, L1 = 4096 + tid * 16;
  const int sr0 = L0 >> 7, sr1 = L1 >> 7;              // 128B rows
  const int sc0 = ((L0 >> 4) & 7) ^ (sr0 & 7);         // pre-swizzled source col
  const int sc1 = ((L1 >> 4) & 7) ^ (sr1 & 7);
  const unsigned short* kG0 = kb + kbase + (size_t)sr0 * 64 + sc0 * 8;
  const unsigned short* kG1 = kb + kbase + (size_t)sr1 * 64 + sc1 * 8;
  const unsigned short* vG0 = vTb + vbase + (size_t)sr0 * 2048 + sc0 * 8;
  const unsigned short* vG1 = vTb + vbase + (size_t)sr1 * 2048 + sc1 * 8;
  unsigned short* const dK0a = (unsigned short*)lK[0] + (L0 >> 1);
  unsigned short* const dK0b = (unsigned short*)lK[0] + (L1 >> 1);
  unsigned short* const dK1a = (unsigned short*)lK[1] + (L0 >> 1);
  unsigned short* const dK1b = (unsigned short*)lK[1] + (L1 >> 1);
  unsigned short* const dV0a = (unsigned short*)lV[0] + (L0 >> 1);
  unsigned short* const dV0b = (unsigned short*)lV[0] + (L1 >> 1);
  unsigned short* const dV1a = (unsigned short*)lV[1] + (L0 >> 1);
  unsigned short* const dV1b = (unsigned short*)lV[1] + (L1 >> 1);

#define ATTN_STAGE(B) do {                        \
    GLD16(kG0, dK##B##a); GLD16(kG1, dK##B##b);   \
    GLD16(vG0, dV##B##a); GLD16(vG1, dV##B##b);   \
    kG0 += 4096; kG1 += 4096; vG0 += 64; vG1 += 64; } while (0)

  ATTN_STAGE(0);  // stage tile 0 (overlaps Q build below); ptrs now at tile 1

  const float LOG2E = 1.44269504088896f;
  const float hs = hsc[h];
  float dir8[8];
#pragma unroll
  for (int j2 = 0; j2 < 8; ++j2) dir8[j2] = hdir[h * 8 + j2];

  // Folded Q~ fragment (B-operand of swapped QK^T): lane holds Q~[q=r][d-chunk g].
  u16x8 qc0, qc1;
  {
    const unsigned short* qrow = qb + ((size_t)bh * 2048 + qbase + wid * 16 + r) * 64;
    float proj = 0.f;
    u16x8 qv = *(const u16x8*)qrow;
#pragma unroll
    for (int j2 = 0; j2 < 8; ++j2) proj += bf2f(qv[j2]) * dir8[j2];
#pragma unroll
    for (int s = 0; s < 2; ++s) {
      u16x8 raw = *(const u16x8*)(qrow + s * 32 + g * 8);
      u16x8 ov;
#pragma unroll
      for (int j2 = 0; j2 < 8; ++j2) {
        float v = bf2f(raw[j2]) * (0.125f * LOG2E);
        if (s == 0 && g == 0) v += (hs * LOG2E) * proj * dir8[j2];
        ov[j2] = f2bf(v);
      }
      if (s == 0) qc0 = ov; else qc1 = ov;
    }
  }

  // --- hoisted LDS fragment pointers (loop-invariant; indexed by literals only) ---
  const int swz = (r & 7) << 4;
  const u16x8* kp[2][8];
  const u16x8* vp[2][8];
#pragma unroll
  for (int b = 0; b < 2; ++b) {
    const char* kc = (const char*)lK[b];
    const char* vc = (const char*)lV[b];
#pragma unroll
    for (int ct = 0; ct < 4; ++ct) {
      int krow = ct * 16 + r, sw = (krow & 7) << 4;
      kp[b][ct * 2 + 0] = (const u16x8*)(kc + krow * 128 + ((g * 16) ^ sw));
      kp[b][ct * 2 + 1] = (const u16x8*)(kc + krow * 128 + ((64 + g * 16) ^ sw));
    }
#pragma unroll
    for (int s = 0; s < 2; ++s)
#pragma unroll
      for (int dt = 0; dt < 4; ++dt) {
        int dd = dt * 16 + r;
        vp[b][s * 4 + dt] = (const u16x8*)(vc + dd * 128 + ((s * 64 + g * 16) ^ ((dd & 7) << 4)));
      }
  }
  unsigned short* pw = &lP[wid][0];
  u32x2* pwr[4];
  const u16x8* prd[2];
#pragma unroll
  for (int ct = 0; ct < 4; ++ct)
    pwr[ct] = (u32x2*)((char*)pw + r * 128 + ((ct * 32 + g * 8) ^ swz));
#pragma unroll
  for (int s = 0; s < 2; ++s)
    prd[s] = (const u16x8*)((const char*)pw + r * 128 + ((s * 64 + g * 16) ^ swz));

  f32x4 accO[4] = {};
  float lp = 0.f;   // LANE-PARTIAL denominator (reduced once in epilogue)
  const int qq = qbase + wid * 16 + r;

  // prologue: tile 0 staged & published
  asm volatile("s_waitcnt vmcnt(0)" ::: "memory");
  __builtin_amdgcn_sched_barrier(0);
  __builtin_amdgcn_s_barrier();

#define ATTN_BODY(B, KT) do {                                                  \
    f32x4 accS[4];                                                             \
    __builtin_amdgcn_s_setprio(1);                                             \
    _Pragma("unroll")                                                          \
    for (int ct = 0; ct < 4; ++ct) {                                           \
      f32x4 s4 = {0.f, 0.f, 0.f, 0.f};                                         \
      s4 = mfma16(*kp[B][ct * 2 + 0], qc0, s4);                                \
      s4 = mfma16(*kp[B][ct * 2 + 1], qc1, s4);                                \
      accS[ct] = s4;                                                           \
    }                                                                          \
    __builtin_amdgcn_s_setprio(0);                                             \
    if ((KT) == nk - 1) {                                                      \
      _Pragma("unroll")                                                        \
      for (int ct = 0; ct < 4; ++ct)                                           \
        _Pragma("unroll")                                                      \
        for (int e = 0; e < 4; ++e) {                                          \
          int kk = (KT) * 64 + ct * 16 + g * 4 + e;                            \
          if (kk > qq) accS[ct][e] = -1e30f;                                   \
        }                                                                      \
    }                                                                          \
    float p[4][4];                                                             \
    _Pragma("unroll")                                                          \
    for (int ct = 0; ct < 4; ++ct)                                             \
      _Pragma("unroll")                                                        \
      for (int e = 0; e < 4; ++e) p[ct][e] = exp2f(accS[ct][e]);               \
    _Pragma("unroll")                                                          \
    for (int ct = 0; ct < 4; ++ct)                                             \
      lp += (p[ct][0] + p[ct][1]) + (p[ct][2] + p[ct][3]);                     \
    _Pragma("unroll")                                                          \
    for (int ct = 0; ct < 4; ++ct) {                                           \
      u32x2 w;                                                                 \
      w[0] = cvtpk(p[ct][0], p[ct][1]);                                        \
      w[1] = cvtpk(p[ct][2], p[ct][3]);                                        \
      *pwr[ct] = w;                                                            \
    }                                                                          \
    asm volatile("s_waitcnt lgkmcnt(0)" ::: "memory");                         \
    __builtin_amdgcn_sched_barrier(0);                                         \
    __builtin_amdgcn_s_setprio(1);                                             \
    _Pragma("unroll")                                                          \
    for (int s = 0; s < 2; ++s) {                                              \
      u16x8 pa = *prd[s];                                                      \
      _Pragma("unroll")                                                        \
      for (int dt = 0; dt < 4; ++dt)                                           \
        accO[dt] = mfma16(*vp[B][s * 4 + dt], pa, accO[dt]);                   \
    }                                                                          \
    __builtin_amdgcn_s_setprio(0);                                             \
  } while (0)

#define ATTN_SYNC() do {                                  \
    asm volatile("s_waitcnt vmcnt(0)" ::: "memory");      \
    __builtin_amdgcn_sched_barrier(0);                    \
    __builtin_amdgcn_s_barrier(); } while (0)

  int kt = 0;
  for (;;) {
    if (kt + 1 < nk) ATTN_STAGE(1);
    ATTN_BODY(0, kt);
    ++kt; if (kt == nk) break;
    ATTN_SYNC();
    if (kt + 1 < nk) ATTN_STAGE(0);
    ATTN_BODY(1, kt);
    ++kt; if (kt == nk) break;
    ATTN_SYNC();
  }
#undef ATTN_BODY
#undef ATTN_STAGE
#undef ATTN_SYNC

  // epilogue: reduce lane-partial l once, then O/l -> bf16 [B,T,C]
  lp += __shfl_xor(lp, 16, 64);
  lp += __shfl_xor(lp, 32, 64);
  float inv = 1.f / lp;
#pragma unroll
  for (int dt = 0; dt < 4; ++dt) {
    u16x4 o;
#pragma unroll
    for (int e = 0; e < 4; ++e) o[e] = f2bf(accO[dt][e] * inv);
    *(u16x4*)(o2 + ((size_t)(bi * 2048 + qq)) * 1024 + h * 64 + dt * 16 + g * 4) = o;
  }
}

extern "C" void kernel_launch(void* const* d_in, const int* in_sizes, int n_in,
                              void* d_out, int out_size, void* d_ws, size_t ws_size,
                              hipStream_t stream) {
  const float* x    = (const float*)d_in[0];
  const float* wqkv = (const float*)d_in[1];
  const float* wout = (const float*)d_in[2];
  const float* hsc  = (const float*)d_in[3];
  const float* hdir = (const float*)d_in[4];
  float* outp = (float*)d_out;

  char* ws = (char*)d_ws;
  unsigned short* xb    = (unsigned short*)(ws + 0);         //  8 MB  [4096][1024]
  unsigned short* wqkvT = (unsigned short*)(ws + 8388608);   //  6 MB  [3072][1024]
  unsigned short* woutT = (unsigned short*)(ws + 14680064);  //  2 MB  [1024][1024]
  unsigned short* qb    = (unsigned short*)(ws + 16777216);  //  8 MB  [32][2048][64]
  unsigned short* kb    = (unsigned short*)(ws + 25165824);  //  8 MB  [32][2048][64]
  unsigned short* vT    = (unsigned short*)(ws + 33554432);  //  8 MB  [32][64][2048]
  unsigned short* x2b   = (unsigned short*)(ws + 41943040);  //  8 MB  [4096][1024]
  if (ws_size < 50331648u) return;

  k_prep<<<5120, 256, 0, stream>>>(x, wqkv, wout, xb, wqkvT, woutT);
  k_gemm_qkv<<<dim3(24, 32), 256, 0, stream>>>(xb, wqkvT, qb, kb, vT);
  k_attn<<<dim3(1024), 256, 0, stream>>>(qb, kb, vT, hsc, hdir, x2b);
  k_gout<<<dim3(16, 32), 256, 0, stream>>>(x2b, woutT, outp);
}